// Round 12
// baseline (226.416 us; speedup 1.0000x reference)
//
#include <hip/hip_runtime.h>
#include <hip/hip_bf16.h>

typedef __attribute__((ext_vector_type(8)))  short s8v;   // 8 bf16
typedef __attribute__((ext_vector_type(4)))  float f4v;   // 16x16 C/D
typedef _Float16 h4 __attribute__((ext_vector_type(4)));  // 4 f16
typedef unsigned int u32x4 __attribute__((ext_vector_type(4)));
typedef unsigned int u32x2 __attribute__((ext_vector_type(2)));

constexpr int Dd   = 256;
constexpr int NCn  = 128;
constexpr int DDn  = 65536;
constexpr int PPn  = 4 * DDn;
constexpr size_t TB = (size_t)NCn * 4096;
constexpr int XP   = 264;             // padded LDS row (bf16 elems)
constexpr float EPSf = 1.1920929e-07f;

__device__ __forceinline__ float sigm(float x){ return 1.0f/(1.0f + expf(-x)); }
__device__ __forceinline__ float silu_(float x){ return x * sigm(x); }

__device__ __forceinline__ unsigned short f2b(float x){
    __hip_bfloat16 b = __float2bfloat16(x);
    unsigned short u; __builtin_memcpy(&u, &b, 2); return u;
}
__device__ __forceinline__ float b2f(unsigned short u){
    __hip_bfloat16 b; __builtin_memcpy(&b, &u, 2); return __bfloat162float(b);
}
__device__ __forceinline__ unsigned short f2hu(float x){
    _Float16 h = (_Float16)x;
    unsigned short u; __builtin_memcpy(&u, &h, 2); return u;
}
__device__ __forceinline__ h4 ldh4(const unsigned short* p){
    h4 r; __builtin_memcpy(&r, p, 8); return r;
}
// non-temporal helpers (L2-bypass hints) — ext_vector int types for the builtin
__device__ __forceinline__ void nts16(unsigned short* p, s8v v){
    u32x4 u; __builtin_memcpy(&u, &v, 16);
    __builtin_nontemporal_store(u, (u32x4*)p);
}
__device__ __forceinline__ void nts8(unsigned short* p, ushort4 v){
    u32x2 u; __builtin_memcpy(&u, &v, 8);
    __builtin_nontemporal_store(u, (u32x2*)p);
}
__device__ __forceinline__ s8v ntl16(const unsigned short* p){
    u32x4 u = __builtin_nontemporal_load((const u32x4*)p);
    s8v v; __builtin_memcpy(&v, &u, 16); return v;
}

// ---- merged prep: b<128 chunk norms+gates; b>=128 weight transposes/casts ----
__global__ __launch_bounds__(256) void kprep(const float* __restrict__ seq,
        const float* __restrict__ wsn, const float* __restrict__ wrn,
        const float* __restrict__ wa, const float* __restrict__ wm,
        const float* __restrict__ wdk,
        const float* __restrict__ Wq, const float* __restrict__ Wkv,
        const float* __restrict__ W0, const float* __restrict__ W1,
        const float* __restrict__ W2, const float* __restrict__ W3,
        unsigned short* __restrict__ snb, unsigned short* __restrict__ rnb,
        unsigned short* __restrict__ WTb, unsigned short* __restrict__ Wb,
        unsigned short* __restrict__ WqTb, unsigned short* __restrict__ WkvTb,
        float* __restrict__ lrg, float* __restrict__ momg, float* __restrict__ decg){
    __shared__ float ltile[32*33];
    __shared__ float lcm[1024];
    __shared__ float lred[4];
    int tid = threadIdx.x, b = blockIdx.x;
    int w = tid >> 6, lane = tid & 63;
    if (b < 128){
        int g = b;
        float cmp[4] = {0,0,0,0};
        for (int cc = 0; cc < 4; ++cc){
            int c = w*4 + cc;
            size_t tb_ = ((size_t)g*16 + c)*256;
            float x0 = seq[tb_ + lane],       x1 = seq[tb_ + lane + 64];
            float x2 = seq[tb_ + lane + 128], x3 = seq[tb_ + lane + 192];
            float ss = x0*x0 + x1*x1 + x2*x2 + x3*x3;
            #pragma unroll
            for (int off = 32; off; off >>= 1) ss += __shfl_xor(ss, off, 64);
            float r = rsqrtf(ss*(1.f/256.f) + EPSf);
            float s0 = x0*r*wsn[lane],     s1 = x1*r*wsn[lane+64];
            float s2 = x2*r*wsn[lane+128], s3 = x3*r*wsn[lane+192];
            snb[tb_ + lane]       = f2b(s0);
            snb[tb_ + lane + 64]  = f2b(s1);
            snb[tb_ + lane + 128] = f2b(s2);
            snb[tb_ + lane + 192] = f2b(s3);
            cmp[0] += s0; cmp[1] += s1; cmp[2] += s2; cmp[3] += s3;
            int tl = (g & 63)*16 + c;
            float r0 = 0.f, r1 = 0.f, r2 = 0.f, r3 = 0.f;
            if (tl <= 1008){
                size_t t2 = (((size_t)(g >> 6))*1024 + tl + 15)*256;
                float y0 = seq[t2 + lane],       y1 = seq[t2 + lane + 64];
                float y2 = seq[t2 + lane + 128], y3 = seq[t2 + lane + 192];
                float s2s = y0*y0 + y1*y1 + y2*y2 + y3*y3;
                #pragma unroll
                for (int off = 32; off; off >>= 1) s2s += __shfl_xor(s2s, off, 64);
                float rr = rsqrtf(s2s*(1.f/256.f) + EPSf);
                r0 = y0*rr*wrn[lane];     r1 = y1*rr*wrn[lane+64];
                r2 = y2*rr*wrn[lane+128]; r3 = y3*rr*wrn[lane+192];
            }
            rnb[tb_ + lane]       = f2b(r0);
            rnb[tb_ + lane + 64]  = f2b(r1);
            rnb[tb_ + lane + 128] = f2b(r2);
            rnb[tb_ + lane + 192] = f2b(r3);
        }
        #pragma unroll
        for (int k = 0; k < 4; ++k) lcm[w*256 + k*64 + lane] = cmp[k];
        __syncthreads();
        int d = tid;
        float cm = (lcm[d] + lcm[256+d] + lcm[512+d] + lcm[768+d]) * (1.f/16.f);
        float vals[3] = {cm*wa[d], cm*wm[d], cm*wdk[d]};
        float sums[3];
        #pragma unroll
        for (int q = 0; q < 3; ++q){
            float v = vals[q];
            #pragma unroll
            for (int off = 32; off; off >>= 1) v += __shfl_down(v, off, 64);
            if (lane == 0) lred[w] = v;
            __syncthreads();
            sums[q] = lred[0] + lred[1] + lred[2] + lred[3];
            __syncthreads();
        }
        if (tid == 0){
            lrg[g]  = sigm(sums[0]);
            momg[g] = sigm(sums[1]);
            decg[g] = sigm(sums[2]);
        }
    } else {
        int b2 = b - 128;   // 0..31
        for (int tj = b2; tj < 448; tj += 32){
            const float* S; unsigned short* T; int C; int t0;
            if (tj < 256){
                int z = tj >> 6; t0 = tj & 63;
                S = (z==0)?W0:(z==1)?W1:(z==2)?W2:W3;
                T = WTb + (size_t)z*DDn; C = 256;
            } else if (tj < 320){ t0 = tj - 256; S = Wq; T = WqTb; C = 256; }
            else { t0 = tj - 320; S = Wkv; T = WkvTb; C = 512; }
            int k0 = (t0 & 7)*32, j0 = (t0 >> 3)*32;
            int tx = tid & 31, ty = tid >> 5;
            __syncthreads();
            #pragma unroll
            for (int p = 0; p < 4; ++p)
                ltile[(ty + 8*p)*33 + tx] = S[(size_t)(k0 + ty + 8*p)*C + j0 + tx];
            __syncthreads();
            #pragma unroll
            for (int p = 0; p < 4; ++p)
                T[(size_t)(j0 + ty + 8*p)*256 + k0 + tx] = f2b(ltile[tx*33 + ty + 8*p]);
        }
        for (int i = b2*256 + tid; i < 98304; i += 8192){
            int z = i / 32768, off = i - z*32768;
            const float* S = (z==0)?W1:(z==1)?W2:W3;
            float2 v = *(const float2*)(S + (size_t)off*2);
            ushort2 u; u.x = f2b(v.x); u.y = f2b(v.y);
            *(ushort2*)(Wb + (size_t)z*DDn + (size_t)off*2) = u;
        }
    }
}

// ---- q projection: xq0 = rn @ Wq (bf16), streaming, no LDS ----
__global__ __launch_bounds__(256, 1) void kqproj(const unsigned short* __restrict__ rnb,
        const unsigned short* __restrict__ WqTb, unsigned short* __restrict__ xq0){
    int lane = threadIdx.x & 63, w = threadIdx.x >> 6;
    int m16 = lane & 15, q16 = lane >> 4;
    int g = blockIdx.y, n0 = blockIdx.x*64 + w*16;
    s8v a[8];
    const unsigned short* ar = rnb + (size_t)g*4096 + m16*256 + q16*8;
    #pragma unroll
    for (int i = 0; i < 8; ++i) a[i] = *(const s8v*)(ar + i*32);
    f4v acc = {0.f,0.f,0.f,0.f};
    const unsigned short* bw = WqTb + (size_t)(n0 + m16)*256 + q16*8;
    #pragma unroll
    for (int i = 0; i < 8; ++i){
        s8v b = *(const s8v*)(bw + i*32);
        acc = __builtin_amdgcn_mfma_f32_16x16x32_bf16(a[i], b, acc, 0, 0, 0);
    }
    #pragma unroll
    for (int r = 0; r < 4; ++r)
        xq0[(size_t)g*4096 + (4*q16 + r)*256 + n0 + m16] = f2b(acc[r]);
}

// ---- fwd + bwd dgrads; grid (2,128): bh=0 fwd->XT, bh=1 fwd+bwd->GT ----
__global__ __launch_bounds__(512, 1) void kfb(const unsigned short* __restrict__ snb,
        const unsigned short* __restrict__ WkvTb, const unsigned short* __restrict__ WTb,
        const unsigned short* __restrict__ Wb, const float* __restrict__ lrg,
        unsigned short* __restrict__ XT, unsigned short* __restrict__ GT){
    __shared__ unsigned short xl[4][16][XP];
    __shared__ unsigned short Gs[16][XP];
    int tid = threadIdx.x, w = tid >> 6, lane = tid & 63;
    int m16 = lane & 15, q16 = lane >> 4;
    int g = blockIdx.y, bh = blockIdx.x;
    float sc = -2.f * lrg[g] * (1.f/256.f);

    s8v af[8];
    const unsigned short* arow = snb + (size_t)g*4096 + m16*256 + q16*8;
    #pragma unroll
    for (int i = 0; i < 8; ++i) af[i] = *(const s8v*)(arow + i*32);

    f4v vacc[2];
    #pragma unroll
    for (int t = 0; t < 2; ++t){
        int n0 = w*32 + t*16;
        f4v ka = {0.f,0.f,0.f,0.f}, va = {0.f,0.f,0.f,0.f};
        const unsigned short* brK = WkvTb + (size_t)(n0 + m16)*256 + q16*8;
        const unsigned short* brV = WkvTb + (size_t)(256 + n0 + m16)*256 + q16*8;
        #pragma unroll
        for (int i = 0; i < 8; ++i){
            s8v bK = *(const s8v*)(brK + i*32);
            s8v bV = *(const s8v*)(brV + i*32);
            ka = __builtin_amdgcn_mfma_f32_16x16x32_bf16(af[i], bK, ka, 0, 0, 0);
            va = __builtin_amdgcn_mfma_f32_16x16x32_bf16(af[i], bV, va, 0, 0, 0);
        }
        vacc[t] = va;
        #pragma unroll
        for (int r = 0; r < 4; ++r) xl[0][4*q16 + r][n0 + m16] = f2b(ka[r]);
    }

    f4v hreg[3][2];
    for (int l = 0; l < 3; ++l){
        __syncthreads();
        s8v xa[8];
        #pragma unroll
        for (int i = 0; i < 8; ++i)
            xa[i] = *(const s8v*)(&xl[l][m16][q16*8 + i*32]);
        const unsigned short* Wt = WTb + (size_t)l*DDn;
        #pragma unroll
        for (int t = 0; t < 2; ++t){
            int n0 = w*32 + t*16;
            f4v acc = {0.f,0.f,0.f,0.f};
            const unsigned short* br = Wt + (size_t)(n0 + m16)*256 + q16*8;
            #pragma unroll
            for (int i = 0; i < 8; ++i){
                s8v b = *(const s8v*)(br + i*32);
                acc = __builtin_amdgcn_mfma_f32_16x16x32_bf16(xa[i], b, acc, 0, 0, 0);
            }
            hreg[l][t] = acc;
            #pragma unroll
            for (int r = 0; r < 4; ++r)
                xl[l+1][4*q16 + r][n0 + m16] = f2b(silu_(acc[r]));
        }
    }
    __syncthreads();

    if (bh == 0){   // write f16 transposed activations XT[l][g][d][c], nt
        int d = tid & 255, half = tid >> 8;
        #pragma unroll
        for (int l = 0; l < 4; ++l){
            s8v v;
            #pragma unroll
            for (int j = 0; j < 8; ++j)
                v[j] = (short)f2hu(b2f(xl[l][half*8 + j][d]));
            nts16(XT + (((size_t)l*128 + g)*256 + d)*16 + half*8, v);
        }
        return;
    }

    {   // layer 3 (pred) -> G4
        s8v xa[8];
        #pragma unroll
        for (int i = 0; i < 8; ++i)
            xa[i] = *(const s8v*)(&xl[3][m16][q16*8 + i*32]);
        const unsigned short* Wt = WTb + (size_t)3*DDn;
        #pragma unroll
        for (int t = 0; t < 2; ++t){
            int n0 = w*32 + t*16;
            f4v acc = {0.f,0.f,0.f,0.f};
            const unsigned short* br = Wt + (size_t)(n0 + m16)*256 + q16*8;
            #pragma unroll
            for (int i = 0; i < 8; ++i){
                s8v b = *(const s8v*)(br + i*32);
                acc = __builtin_amdgcn_mfma_f32_16x16x32_bf16(xa[i], b, acc, 0, 0, 0);
            }
            #pragma unroll
            for (int r = 0; r < 4; ++r)
                Gs[4*q16 + r][n0 + m16] = f2b(sc * (acc[r] - vacc[t][r]));
        }
    }
    __syncthreads();
    {
        int d = tid & 255, half = tid >> 8;
        s8v v;
        #pragma unroll
        for (int j = 0; j < 8; ++j)
            v[j] = (short)f2hu(b2f(Gs[half*8 + j][d]));
        nts16(GT + (((size_t)3*128 + g)*256 + d)*16 + half*8, v);
    }

    for (int l = 3; l >= 1; --l){
        s8v gfa[8];
        #pragma unroll
        for (int i = 0; i < 8; ++i)
            gfa[i] = *(const s8v*)(&Gs[m16][q16*8 + i*32]);
        const unsigned short* Wr = Wb + (size_t)(l-1)*DDn;
        f4v gn[2];
        #pragma unroll
        for (int t = 0; t < 2; ++t){
            int n0 = w*32 + t*16;
            f4v acc = {0.f,0.f,0.f,0.f};
            const unsigned short* br = Wr + (size_t)(n0 + m16)*256 + q16*8;
            #pragma unroll
            for (int i = 0; i < 8; ++i){
                s8v b = *(const s8v*)(br + i*32);
                acc = __builtin_amdgcn_mfma_f32_16x16x32_bf16(gfa[i], b, acc, 0, 0, 0);
            }
            #pragma unroll
            for (int r = 0; r < 4; ++r){
                float h = hreg[l-1][t][r];
                float s = sigm(h);
                gn[t][r] = acc[r] * (s*(1.f + h*(1.f - s)));
            }
        }
        __syncthreads();
        #pragma unroll
        for (int t = 0; t < 2; ++t){
            int n0 = w*32 + t*16;
            #pragma unroll
            for (int r = 0; r < 4; ++r)
                Gs[4*q16 + r][n0 + m16] = f2b(gn[t][r]);
        }
        __syncthreads();
        {
            int d = tid & 255, half = tid >> 8;
            s8v v;
            #pragma unroll
            for (int j = 0; j < 8; ++j)
                v[j] = (short)f2hu(b2f(Gs[half*8 + j][d]));
            nts16(GT + (((size_t)(l-1)*128 + g)*256 + d)*16 + half*8, v);
        }
    }
}

// ---- fused outer-product + scans -> updates (bf16), nt vectorized stores ----
__global__ __launch_bounds__(64, 1) void kupd(const unsigned short* __restrict__ XT,
        const unsigned short* __restrict__ GT, const float* __restrict__ momg,
        const float* __restrict__ decg, unsigned short* __restrict__ supb){
    int lane = threadIdx.x, m16 = lane & 15, q16 = lane >> 4;
    int l = blockIdx.z & 3, b = blockIdx.z >> 2;
    int d0 = blockIdx.x*16, o0 = blockIdx.y*16;
    const unsigned short* xbase = XT + (((size_t)l*128 + b*64)*256 + d0 + m16)*16 + q16*4;
    const unsigned short* gbase = GT + (((size_t)l*128 + b*64)*256 + o0 + m16)*16 + q16*4;
    float ms[4] = {0,0,0,0}, us[4] = {0,0,0,0};
    h4 xa = ldh4(xbase);
    h4 gb = ldh4(gbase);
    for (int n = 0; n < 64; ++n){
        int gg = b*64 + n;
        h4 xan, gbn;
        if (n < 63){
            xan = ldh4(xbase + (size_t)(n+1)*4096);
            gbn = ldh4(gbase + (size_t)(n+1)*4096);
        }
        f4v z = {0.f,0.f,0.f,0.f};
        f4v s = __builtin_amdgcn_mfma_f32_16x16x16f16(xa, gb, z, 0, 0, 0);
        float mo = momg[gg], de = 1.f - decg[gg];
        ushort4 u4;
        #pragma unroll
        for (int r = 0; r < 4; ++r){
            ms[r] = mo*ms[r] + s[r];
            us[r] = de*us[r] + ms[r];
            ((unsigned short*)&u4)[r] = f2b(us[r]);
        }
        nts8(supb + ((size_t)gg*4 + l)*DDn + (size_t)(o0 + m16)*256 + d0 + q16*4, u4);
        xa = xan; gb = gbn;
    }
}

// ---- one retrieval MLP layer; nt loads for the read-once U stream ----
__global__ __launch_bounds__(256, 1) void klayer(const unsigned short* __restrict__ Xin,
        const unsigned short* __restrict__ Wt, const unsigned short* __restrict__ supb,
        int l, unsigned short* __restrict__ Xout){
    int lane = threadIdx.x & 63, w = threadIdx.x >> 6;
    int m16 = lane & 15, q16 = lane >> 4;
    int g = blockIdx.y, n0 = blockIdx.x*64 + w*16;
    s8v a[8];
    const unsigned short* ar = Xin + (size_t)g*4096 + m16*256 + q16*8;
    #pragma unroll
    for (int i = 0; i < 8; ++i) a[i] = *(const s8v*)(ar + i*32);
    f4v acc = {0.f,0.f,0.f,0.f};
    const unsigned short* bw = Wt + (size_t)(n0 + m16)*256 + q16*8;
    const unsigned short* bu = supb + (size_t)l*DDn + (size_t)g*PPn
                               + (size_t)(n0 + m16)*256 + q16*8;
    #pragma unroll
    for (int i = 0; i < 8; ++i){
        s8v bW = *(const s8v*)(bw + i*32);
        s8v bU = ntl16(bu + i*32);
        acc = __builtin_amdgcn_mfma_f32_16x16x32_bf16(a[i], bW, acc, 0, 0, 0);
        acc = __builtin_amdgcn_mfma_f32_16x16x32_bf16(a[i], bU, acc, 0, 0, 0);
    }
    #pragma unroll
    for (int r = 0; r < 4; ++r)
        Xout[(size_t)g*4096 + (4*q16 + r)*256 + n0 + m16] = f2b(silu_(acc[r]));
}

// ---- final fast-weight layer + post rmsnorm + shift + zero rows, fused ----
__global__ __launch_bounds__(256, 1) void klast(const unsigned short* __restrict__ Xin,
        const unsigned short* __restrict__ Wt, const unsigned short* __restrict__ supb,
        const float* __restrict__ wpost, float* __restrict__ out){
    __shared__ float red[4][16];
    __shared__ float rs[16];
    int tid = threadIdx.x, w = tid >> 6, lane = tid & 63;
    int m16 = lane & 15, q16 = lane >> 4;
    int g = blockIdx.x, b = g >> 6, nl = g & 63;
    s8v a[8];
    const unsigned short* ar = Xin + (size_t)g*4096 + m16*256 + q16*8;
    #pragma unroll
    for (int i = 0; i < 8; ++i) a[i] = *(const s8v*)(ar + i*32);
    f4v acc[4];
    #pragma unroll
    for (int t = 0; t < 4; ++t){
        int n0 = w*64 + t*16;
        f4v ac = {0.f,0.f,0.f,0.f};
        const unsigned short* bw = Wt + (size_t)(n0 + m16)*256 + q16*8;
        const unsigned short* bu = supb + (size_t)3*DDn + (size_t)g*PPn
                                   + (size_t)(n0 + m16)*256 + q16*8;
        #pragma unroll
        for (int i = 0; i < 8; ++i){
            s8v bW = *(const s8v*)(bw + i*32);
            s8v bU = ntl16(bu + i*32);
            ac = __builtin_amdgcn_mfma_f32_16x16x32_bf16(a[i], bW, ac, 0, 0, 0);
            ac = __builtin_amdgcn_mfma_f32_16x16x32_bf16(a[i], bU, ac, 0, 0, 0);
        }
        acc[t] = ac;
    }
    float part[4] = {0,0,0,0};
    #pragma unroll
    for (int t = 0; t < 4; ++t)
        #pragma unroll
        for (int r = 0; r < 4; ++r) part[r] += acc[t][r]*acc[t][r];
    #pragma unroll
    for (int off = 1; off < 16; off <<= 1)
        #pragma unroll
        for (int r = 0; r < 4; ++r) part[r] += __shfl_xor(part[r], off, 64);
    if (m16 == 0)
        #pragma unroll
        for (int r = 0; r < 4; ++r) red[w][4*q16 + r] = part[r];
    __syncthreads();
    if (tid < 16){
        float s = red[0][tid] + red[1][tid] + red[2][tid] + red[3][tid];
        rs[tid] = rsqrtf(s*(1.f/256.f) + EPSf);
    }
    __syncthreads();
    #pragma unroll
    for (int t = 0; t < 4; ++t){
        int d = w*64 + t*16 + m16;
        float wp = wpost[d];
        #pragma unroll
        for (int r = 0; r < 4; ++r){
            int c = 4*q16 + r;
            int tp = nl*16 + c + 15;
            if (tp < 1024)
                out[((size_t)b*1024 + tp)*256 + d] = acc[t][r]*rs[c]*wp;
        }
    }
    if (nl == 0){
        for (int idx = tid; idx < 15*256; idx += 256)
            out[(size_t)b*262144 + idx] = 0.f;
    }
}

extern "C" void kernel_launch(void* const* d_in, const int* in_sizes, int n_in,
                              void* d_out, int out_size, void* d_ws, size_t ws_size,
                              hipStream_t stream) {
    const float* seq     = (const float*)d_in[0];
    const float* w_store = (const float*)d_in[1];
    const float* w_retr  = (const float*)d_in[2];
    const float* w_post  = (const float*)d_in[3];
    const float* Wq      = (const float*)d_in[4];
    const float* Wkv     = (const float*)d_in[5];
    const float* w_adapt = (const float*)d_in[6];
    const float* w_mom   = (const float*)d_in[7];
    const float* w_decay = (const float*)d_in[8];
    const float* W0      = (const float*)d_in[9];
    const float* W1      = (const float*)d_in[10];
    const float* W2      = (const float*)d_in[11];
    const float* W3      = (const float*)d_in[12];

    float* lrg   = (float*)d_ws;
    float* momg  = lrg + NCn;
    float* decg  = momg + NCn;
    unsigned short* p = (unsigned short*)(decg + NCn + 32);
    unsigned short* snb   = p;            p += TB;
    unsigned short* rnb   = p;            p += TB;
    unsigned short* WTb   = p;            p += 4*(size_t)DDn;
    unsigned short* Wb    = p;            p += 3*(size_t)DDn;
    unsigned short* WqTb  = p;            p += (size_t)DDn;
    unsigned short* WkvTb = p;            p += 2*(size_t)DDn;
    unsigned short* XT    = p;            p += 4*TB;   // f16
    unsigned short* GT    = p;            p += 4*TB;   // f16
    unsigned short* xq0   = p;            p += TB;
    unsigned short* xq1   = p;            p += TB;
    unsigned short* supb  = p;                          // 64*TB bf16 (67MB)

    kprep <<<dim3(160),      256, 0, stream>>>(seq, w_store, w_retr,
                                               w_adapt, w_mom, w_decay,
                                               Wq, Wkv, W0, W1, W2, W3,
                                               snb, rnb, WTb, Wb, WqTb, WkvTb,
                                               lrg, momg, decg);
    kqproj<<<dim3(4, NCn),   256, 0, stream>>>(rnb, WqTb, xq0);
    kfb   <<<dim3(2, NCn),   512, 0, stream>>>(snb, WkvTb, WTb, Wb, lrg, XT, GT);
    kupd  <<<dim3(16, 16, 8), 64, 0, stream>>>(XT, GT, momg, decg, supb);
    klayer<<<dim3(4, NCn),   256, 0, stream>>>(xq0, WTb + 0*(size_t)DDn, supb, 0, xq1);
    klayer<<<dim3(4, NCn),   256, 0, stream>>>(xq1, WTb + 1*(size_t)DDn, supb, 1, xq0);
    klayer<<<dim3(4, NCn),   256, 0, stream>>>(xq0, WTb + 2*(size_t)DDn, supb, 2, xq1);
    klast <<<dim3(NCn),      256, 0, stream>>>(xq1, WTb + 3*(size_t)DDn, supb,
                                               w_post, (float*)d_out);
}